// Round 1
// baseline (319.052 us; speedup 1.0000x reference)
//
#include <hip/hip_runtime.h>
#include <hip/hip_bf16.h>

#define NN 2000
#define NE 8192
#define DIM 10000
#define NCLS 10
#define NCHUNK 32          // edge chunks for stable CSR build
#define CPE 256            // edges per chunk
#define HASH_SZ 32768
#define EBY 16             // edge-chunk blocks for enc kernel

// ---- workspace layout (byte offsets) ----
#define WS_K       0                      // int        (distinct-edge counter)
#define WS_ENC     64                     // f32[10000]
#define WS_DEG     40064                  // int[2000]  (in-degree of col side)
#define WS_BASE    48064                  // int[2001]  (CSR row starts)
#define WS_CHUNK   56128                  // int[32*2000] per-chunk per-node counts -> offsets
#define WS_CCOL    312128                 // u16[8192]  CSR col values (edge-index order per node)
#define WS_V       328512                 // f32[2000]  pagerank result
#define WS_RANK    336512                 // int[2000]  stable rank of each node
#define WS_PAIRS   344512                 // u32[8192]  packed (rank[a]<<16)|rank[b] per distinct edge
#define WS_HASH    377280                 // int[32768] hash set
#define WS_ZERO_BYTES 312128              // zero [0, WS_CCOL)

// ---------- 1. counts: deg (col side) + per-chunk per-node row counts ----------
__global__ __launch_bounds__(256) void count_kernel(const int* __restrict__ eidx,
                                                    int* __restrict__ deg,
                                                    int* __restrict__ chunk) {
  int e = blockIdx.x * CPE + threadIdx.x;
  int r = eidx[e];
  int c = eidx[NE + e];
  atomicAdd(&deg[c], 1);
  atomicAdd(&chunk[blockIdx.x * NN + r], 1);
}

// ---------- 2. scan: node totals -> exclusive base; chunk counts -> chunk offsets ----------
__global__ __launch_bounds__(1024) void scan_kernel(int* __restrict__ base,
                                                    int* __restrict__ chunk) {
  __shared__ int s[2048];
  int tid = threadIdx.x;
  int n0 = tid, n1 = tid + 1024;
  int t0 = 0, t1 = 0;
  for (int b = 0; b < NCHUNK; ++b) t0 += chunk[b * NN + n0];
  if (n1 < NN) for (int b = 0; b < NCHUNK; ++b) t1 += chunk[b * NN + n1];
  s[n0] = t0;
  s[n1] = (n1 < NN) ? t1 : 0;
  __syncthreads();
  for (int dstep = 1; dstep < 2048; dstep <<= 1) {
    int v0 = (n0 >= dstep) ? s[n0 - dstep] : 0;
    int v1 = (n1 >= dstep) ? s[n1 - dstep] : 0;
    __syncthreads();
    s[n0] += v0;
    s[n1] += v1;
    __syncthreads();
  }
  if (tid == 0) base[0] = 0;
  for (int n = tid; n < NN; n += 1024) base[n + 1] = s[n];
  // in-place turn chunk counts into chunk start offsets (stable: chunk-major = edge order)
  for (int n = tid; n < NN; n += 1024) {
    int run = (n == 0) ? 0 : s[n - 1];
    for (int b = 0; b < NCHUNK; ++b) {
      int t = chunk[b * NN + n];
      chunk[b * NN + n] = run;
      run += t;
    }
  }
}

// ---------- 3. stable fill: CSR col list in edge-index order per node ----------
__global__ __launch_bounds__(256) void fill_kernel(const int* __restrict__ eidx,
                                                   const int* __restrict__ chunk,
                                                   unsigned short* __restrict__ ccol) {
  __shared__ int s_rows[CPE];
  int tid = threadIdx.x;
  int e = blockIdx.x * CPE + tid;
  int r = eidx[e];
  int c = eidx[NE + e];
  s_rows[tid] = r;
  __syncthreads();
  int cntb = 0;
  for (int j = 0; j < tid; ++j) cntb += (s_rows[j] == r) ? 1 : 0;
  int slot = chunk[blockIdx.x * NN + r] + cntb;
  ccol[slot] = (unsigned short)c;
}

// ---------- 4. pagerank power iteration (single block, bit-exact f32, edge order) ----------
__global__ __launch_bounds__(1024) void pr_kernel(char* __restrict__ ws) {
  const int* deg_g = (const int*)(ws + WS_DEG);
  const int* base_g = (const int*)(ws + WS_BASE);
  const unsigned short* ccol_g = (const unsigned short*)(ws + WS_CCOL);
  float* vout = (float*)(ws + WS_V);

  __shared__ unsigned short s_ccol[NE];   // 16384 B
  __shared__ float s_val[NN];             // 8000 B: 0.85f/deg[c]
  __shared__ int s_base[NN + 1];          // 8004 B
  __shared__ float s_v[NN];               // 8000 B
  __shared__ float s_red[16];
  __shared__ float s_err;

  int tid = threadIdx.x;
  for (int i = tid; i < NE; i += 1024) s_ccol[i] = ccol_g[i];
  for (int i = tid; i < NN; i += 1024) s_val[i] = 0.85f / (float)deg_g[i]; // inf if deg==0: never used
  for (int i = tid; i <= NN; i += 1024) s_base[i] = base_g[i];
  const float p = 0.0005f;                 // f32(1.0/2000)
  const float addv = 0.0005f * 0.15f;      // p * f32(1.0-0.85)
  for (int i = tid; i < NN; i += 1024) s_v[i] = p;
  __syncthreads();

  float err = __builtin_inff();
  int it = 0;
  while (it < 100 && err >= 0.002f) {
    float vn0 = 0.f, vn1 = 0.f, ep = 0.f;
    {
      int n = tid;
      int s0 = s_base[n], e2 = s_base[n + 1];
      float sum = 0.f;
      for (int k = s0; k < e2; ++k) {
        int c = s_ccol[k];
        sum = __fadd_rn(sum, __fmul_rn(s_val[c], s_v[c]));
      }
      vn0 = __fadd_rn(sum, addv);
      ep += fabsf(__fsub_rn(vn0, s_v[n]));
    }
    if (tid + 1024 < NN) {
      int n = tid + 1024;
      int s0 = s_base[n], e2 = s_base[n + 1];
      float sum = 0.f;
      for (int k = s0; k < e2; ++k) {
        int c = s_ccol[k];
        sum = __fadd_rn(sum, __fmul_rn(s_val[c], s_v[c]));
      }
      vn1 = __fadd_rn(sum, addv);
      ep += fabsf(__fsub_rn(vn1, s_v[tid + 1024]));
    }
    __syncthreads();            // all reads of old s_v done
    s_v[tid] = vn0;
    if (tid + 1024 < NN) s_v[tid + 1024] = vn1;
    for (int o = 32; o > 0; o >>= 1) ep += __shfl_down(ep, o, 64);
    if ((tid & 63) == 0) s_red[tid >> 6] = ep;
    __syncthreads();
    if (tid == 0) {
      float t = 0.f;
      for (int w = 0; w < 16; ++w) t += s_red[w];
      s_err = t;
    }
    __syncthreads();
    err = s_err;
    ++it;
  }
  for (int i = tid; i < NN; i += 1024) vout[i] = s_v[i];
}

// ---------- 5. stable rank (matches stable argsort, ties by index) ----------
__global__ __launch_bounds__(256) void rank_kernel(char* __restrict__ ws) {
  const float* v = (const float*)(ws + WS_V);
  int* rnk = (int*)(ws + WS_RANK);
  int i = blockIdx.x * 256 + threadIdx.x;
  if (i >= NN) return;
  float vi = v[i];
  int r = 0;
  for (int j = 0; j < NN; ++j) {
    float vj = v[j];
    r += ((vj < vi) || (vj == vi && j < i)) ? 1 : 0;
  }
  rnk[i] = r;
}

// ---------- 6. dedup undirected edges via hash set; emit packed ranked pairs ----------
__global__ __launch_bounds__(256) void dedup_kernel(const int* __restrict__ eidx,
                                                    char* __restrict__ ws) {
  int* hash = (int*)(ws + WS_HASH);
  unsigned int* pairs = (unsigned int*)(ws + WS_PAIRS);
  int* Kp = (int*)(ws + WS_K);
  const int* rnk = (const int*)(ws + WS_RANK);
  int e = blockIdx.x * 256 + threadIdx.x;
  int r = eidx[e], c = eidx[NE + e];
  int a = min(r, c), b = max(r, c);
  int key = a * NN + b;
  unsigned int h = ((unsigned int)key * 2654435761u) >> 17;
  for (;;) {
    h &= (HASH_SZ - 1);
    int old = atomicCAS(&hash[h], -1, key);
    if (old == -1) {                       // this edge owns the distinct key
      int idx = atomicAdd(Kp, 1);
      pairs[idx] = ((unsigned int)rnk[a] << 16) | (unsigned int)rnk[b];
      return;
    }
    if (old == key) return;                // duplicate
    ++h;
  }
}

// ---------- 7. enc[d] = sum over distinct edges of W[ra][d]*W[rb][d] (exact ints) ----------
__global__ __launch_bounds__(256) void enc_kernel(const float* __restrict__ W,
                                                  char* __restrict__ ws) {
  const unsigned int* pairs = (const unsigned int*)(ws + WS_PAIRS);
  const int* Kp = (const int*)(ws + WS_K);
  float* enc = (float*)(ws + WS_ENC);
  int d = blockIdx.x * 256 + threadIdx.x;
  if (d >= DIM) return;
  int K = *Kp;
  const int per = (NE + EBY - 1) / EBY;    // 512
  int e0 = blockIdx.y * per;
  int e1 = min(e0 + per, K);
  float acc = 0.f;
  for (int e = e0; e < e1; ++e) {
    unsigned int pk = pairs[e];
    int ra = (int)(pk >> 16), rb = (int)(pk & 0xffffu);
    acc += W[(size_t)ra * DIM + d] * W[(size_t)rb * DIM + d];
  }
  if (e1 > e0) atomicAdd(&enc[d], acc);
}

// ---------- 8. out[c] = enc . Wc[c] ----------
__global__ __launch_bounds__(256) void out_kernel(const float* __restrict__ Wc,
                                                  char* __restrict__ ws,
                                                  float* __restrict__ out) {
  const float* enc = (const float*)(ws + WS_ENC);
  __shared__ float red[4];
  int c = blockIdx.x;
  float s = 0.f;
  for (int d = threadIdx.x; d < DIM; d += 256) s += enc[d] * Wc[c * DIM + d];
  for (int o = 32; o > 0; o >>= 1) s += __shfl_down(s, o, 64);
  if ((threadIdx.x & 63) == 0) red[threadIdx.x >> 6] = s;
  __syncthreads();
  if (threadIdx.x == 0) out[c] = red[0] + red[1] + red[2] + red[3];
}

extern "C" void kernel_launch(void* const* d_in, const int* in_sizes, int n_in,
                              void* d_out, int out_size, void* d_ws, size_t ws_size,
                              hipStream_t stream) {
  const int* eidx = (const int*)d_in[0];        // edge_index int32 [2, 8192]
  const float* Wn = (const float*)d_in[1];      // node_ids_weight f32 [2000, 10000]
  const float* Wc = (const float*)d_in[2];      // classify_weight f32 [10, 10000]
  float* out = (float*)d_out;
  char* ws = (char*)d_ws;

  hipMemsetAsync(ws, 0, WS_ZERO_BYTES, stream);
  hipMemsetAsync(ws + WS_HASH, 0xFF, HASH_SZ * 4, stream);

  count_kernel<<<NCHUNK, CPE, 0, stream>>>(eidx, (int*)(ws + WS_DEG), (int*)(ws + WS_CHUNK));
  scan_kernel<<<1, 1024, 0, stream>>>((int*)(ws + WS_BASE), (int*)(ws + WS_CHUNK));
  fill_kernel<<<NCHUNK, CPE, 0, stream>>>(eidx, (const int*)(ws + WS_CHUNK),
                                          (unsigned short*)(ws + WS_CCOL));
  pr_kernel<<<1, 1024, 0, stream>>>(ws);
  rank_kernel<<<(NN + 255) / 256, 256, 0, stream>>>(ws);
  dedup_kernel<<<NE / 256, 256, 0, stream>>>(eidx, ws);
  enc_kernel<<<dim3((DIM + 255) / 256, EBY), 256, 0, stream>>>(Wn, ws);
  out_kernel<<<NCLS, 256, 0, stream>>>(Wc, ws, out);
}

// Round 2
// 256.901 us; speedup vs baseline: 1.2419x; 1.2419x over previous
//
#include <hip/hip_runtime.h>
#include <hip/hip_bf16.h>

#define NN 2000
#define NE 8192
#define DIM 10000
#define NCLS 10
#define NCHUNK 32          // edge chunks for stable CSR build
#define CPE 256            // edges per chunk
#define HASH_SZ 32768
#define WORDS 313          // ceil(10000/32) packed sign words per node

// ---- workspace layout (byte offsets) ----
#define WS_K       0                      // int        (distinct-edge counter)
#define WS_ENC     64                     // f32[10000]
#define WS_DEG     40064                  // int[2000]  (in-degree of col side)
#define WS_BASE    48064                  // int[2001]  (CSR row starts)
#define WS_CHUNK   56128                  // int[32*2000] per-chunk per-node counts -> offsets
#define WS_CCOL    312128                 // u16[8192]  CSR col values (edge-index order per node)
#define WS_V       328512                 // f32[2000]  pagerank result
#define WS_RANK    336512                 // int[2000]  stable rank of each node
#define WS_PAIRS   344512                 // u32[8192]  packed (rank[a]<<16)|rank[b] per distinct edge
#define WS_HASH    377280                 // int[32768] hash set
#define WS_PACK    508352                 // u32[313*2000] packed sign bits, layout [word][node]
#define WS_ZERO_BYTES 312128              // zero [0, WS_CCOL)

// ---------- 1. counts: deg (col side) + per-chunk per-node row counts ----------
__global__ __launch_bounds__(256) void count_kernel(const int* __restrict__ eidx,
                                                    int* __restrict__ deg,
                                                    int* __restrict__ chunk) {
  int e = blockIdx.x * CPE + threadIdx.x;
  int r = eidx[e];
  int c = eidx[NE + e];
  atomicAdd(&deg[c], 1);
  atomicAdd(&chunk[blockIdx.x * NN + r], 1);
}

// ---------- 2. scan: node totals -> exclusive base; chunk counts -> chunk offsets ----------
__global__ __launch_bounds__(1024) void scan_kernel(int* __restrict__ base,
                                                    int* __restrict__ chunk) {
  __shared__ int s[2048];
  int tid = threadIdx.x;
  int n0 = tid, n1 = tid + 1024;
  int t0 = 0, t1 = 0;
  for (int b = 0; b < NCHUNK; ++b) t0 += chunk[b * NN + n0];
  if (n1 < NN) for (int b = 0; b < NCHUNK; ++b) t1 += chunk[b * NN + n1];
  s[n0] = t0;
  s[n1] = (n1 < NN) ? t1 : 0;
  __syncthreads();
  for (int dstep = 1; dstep < 2048; dstep <<= 1) {
    int v0 = (n0 >= dstep) ? s[n0 - dstep] : 0;
    int v1 = (n1 >= dstep) ? s[n1 - dstep] : 0;
    __syncthreads();
    s[n0] += v0;
    s[n1] += v1;
    __syncthreads();
  }
  if (tid == 0) base[0] = 0;
  for (int n = tid; n < NN; n += 1024) base[n + 1] = s[n];
  // in-place turn chunk counts into chunk start offsets (stable: chunk-major = edge order)
  for (int n = tid; n < NN; n += 1024) {
    int run = (n == 0) ? 0 : s[n - 1];
    for (int b = 0; b < NCHUNK; ++b) {
      int t = chunk[b * NN + n];
      chunk[b * NN + n] = run;
      run += t;
    }
  }
}

// ---------- 3. stable fill: CSR col list in edge-index order per node ----------
__global__ __launch_bounds__(256) void fill_kernel(const int* __restrict__ eidx,
                                                   const int* __restrict__ chunk,
                                                   unsigned short* __restrict__ ccol) {
  __shared__ int s_rows[CPE];
  int tid = threadIdx.x;
  int e = blockIdx.x * CPE + tid;
  int r = eidx[e];
  int c = eidx[NE + e];
  s_rows[tid] = r;
  __syncthreads();
  int cntb = 0;
  for (int j = 0; j < tid; ++j) cntb += (s_rows[j] == r) ? 1 : 0;
  int slot = chunk[blockIdx.x * NN + r] + cntb;
  ccol[slot] = (unsigned short)c;
}

// ---------- 4. pagerank power iteration (single block, bit-exact f32, edge order) ----------
__global__ __launch_bounds__(1024) void pr_kernel(char* __restrict__ ws) {
  const int* deg_g = (const int*)(ws + WS_DEG);
  const int* base_g = (const int*)(ws + WS_BASE);
  const unsigned short* ccol_g = (const unsigned short*)(ws + WS_CCOL);
  float* vout = (float*)(ws + WS_V);

  __shared__ unsigned short s_ccol[NE];   // 16384 B
  __shared__ float s_val[NN];             // 8000 B: 0.85f/deg[c]
  __shared__ int s_base[NN + 1];          // 8004 B
  __shared__ float s_v[NN];               // 8000 B
  __shared__ float s_red[16];
  __shared__ float s_err;

  int tid = threadIdx.x;
  for (int i = tid; i < NE; i += 1024) s_ccol[i] = ccol_g[i];
  for (int i = tid; i < NN; i += 1024) s_val[i] = 0.85f / (float)deg_g[i]; // inf if deg==0: never used
  for (int i = tid; i <= NN; i += 1024) s_base[i] = base_g[i];
  const float p = 0.0005f;                 // f32(1.0/2000)
  const float addv = 0.0005f * 0.15f;      // p * f32(1.0-0.85)
  for (int i = tid; i < NN; i += 1024) s_v[i] = p;
  __syncthreads();

  float err = __builtin_inff();
  int it = 0;
  while (it < 100 && err >= 0.002f) {
    float vn0 = 0.f, vn1 = 0.f, ep = 0.f;
    {
      int n = tid;
      int s0 = s_base[n], e2 = s_base[n + 1];
      float sum = 0.f;
      for (int k = s0; k < e2; ++k) {
        int c = s_ccol[k];
        sum = __fadd_rn(sum, __fmul_rn(s_val[c], s_v[c]));
      }
      vn0 = __fadd_rn(sum, addv);
      ep += fabsf(__fsub_rn(vn0, s_v[n]));
    }
    if (tid + 1024 < NN) {
      int n = tid + 1024;
      int s0 = s_base[n], e2 = s_base[n + 1];
      float sum = 0.f;
      for (int k = s0; k < e2; ++k) {
        int c = s_ccol[k];
        sum = __fadd_rn(sum, __fmul_rn(s_val[c], s_v[c]));
      }
      vn1 = __fadd_rn(sum, addv);
      ep += fabsf(__fsub_rn(vn1, s_v[tid + 1024]));
    }
    __syncthreads();            // all reads of old s_v done
    s_v[tid] = vn0;
    if (tid + 1024 < NN) s_v[tid + 1024] = vn1;
    for (int o = 32; o > 0; o >>= 1) ep += __shfl_down(ep, o, 64);
    if ((tid & 63) == 0) s_red[tid >> 6] = ep;
    __syncthreads();
    if (tid == 0) {
      float t = 0.f;
      for (int w = 0; w < 16; ++w) t += s_red[w];
      s_err = t;
    }
    __syncthreads();
    err = s_err;
    ++it;
  }
  for (int i = tid; i < NN; i += 1024) vout[i] = s_v[i];
}

// ---------- 5. stable rank (matches stable argsort, ties by index) ----------
__global__ __launch_bounds__(256) void rank_kernel(char* __restrict__ ws) {
  const float* v = (const float*)(ws + WS_V);
  int* rnk = (int*)(ws + WS_RANK);
  int i = blockIdx.x * 256 + threadIdx.x;
  if (i >= NN) return;
  float vi = v[i];
  int r = 0;
  for (int j = 0; j < NN; ++j) {
    float vj = v[j];
    r += ((vj < vi) || (vj == vi && j < i)) ? 1 : 0;
  }
  rnk[i] = r;
}

// ---------- 6. dedup undirected edges via hash set; emit packed ranked pairs ----------
__global__ __launch_bounds__(256) void dedup_kernel(const int* __restrict__ eidx,
                                                    char* __restrict__ ws) {
  int* hash = (int*)(ws + WS_HASH);
  unsigned int* pairs = (unsigned int*)(ws + WS_PAIRS);
  int* Kp = (int*)(ws + WS_K);
  const int* rnk = (const int*)(ws + WS_RANK);
  int e = blockIdx.x * 256 + threadIdx.x;
  int r = eidx[e], c = eidx[NE + e];
  int a = min(r, c), b = max(r, c);
  int key = a * NN + b;
  unsigned int h = ((unsigned int)key * 2654435761u) >> 17;
  for (;;) {
    h &= (HASH_SZ - 1);
    int old = atomicCAS(&hash[h], -1, key);
    if (old == -1) {                       // this edge owns the distinct key
      int idx = atomicAdd(Kp, 1);
      pairs[idx] = ((unsigned int)rnk[a] << 16) | (unsigned int)rnk[b];
      return;
    }
    if (old == key) return;                // duplicate
    ++h;
  }
}

// ---------- 7a. pack sign bits: packed[word][node], bit j = sign(W[node][word*32+j]) ----------
__global__ __launch_bounds__(256) void pack_kernel(const float* __restrict__ W,
                                                   unsigned int* __restrict__ packed) {
  int t = blockIdx.x * 256 + threadIdx.x;
  if (t >= NN * WORDS) return;
  int node = t / WORDS;
  int w = t - node * WORDS;            // consecutive threads -> consecutive words of one node
  int d0 = w * 32;                     // -> fully coalesced 128B-per-lane reads
  const float* p = W + (size_t)node * DIM + d0;
  unsigned int m = 0;
  if (d0 + 32 <= DIM) {
#pragma unroll
    for (int j = 0; j < 32; ++j) m |= (__float_as_uint(p[j]) >> 31) << j;
  } else {
    for (int j = 0; j < DIM - d0; ++j) m |= (__float_as_uint(p[j]) >> 31) << j;
  }
  packed[(size_t)w * NN + node] = m;
}

// ---------- 7b. enc[d] = K - 2 * (# edges with sign xor at dim d)  (exact ints) ----------
__global__ __launch_bounds__(256) void encpop_kernel(char* __restrict__ ws) {
  const unsigned int* packed = (const unsigned int*)(ws + WS_PACK);
  const unsigned int* pairs = (const unsigned int*)(ws + WS_PAIRS);
  const int* Kp = (const int*)(ws + WS_K);
  float* enc = (float*)(ws + WS_ENC);
  __shared__ unsigned int s_col[NN];   // this word's bits for all 2000 rows
  __shared__ int s_cnt[32];
  int w = blockIdx.x;
  int tid = threadIdx.x;
  for (int i = tid; i < NN; i += 256) s_col[i] = packed[(size_t)w * NN + i];
  if (tid < 32) s_cnt[tid] = 0;
  __syncthreads();
  int K = *Kp;
  int cnt[32];
#pragma unroll
  for (int b = 0; b < 32; ++b) cnt[b] = 0;
  for (int e = tid; e < K; e += 256) {
    unsigned int pk = pairs[e];
    unsigned int x = s_col[pk >> 16] ^ s_col[pk & 0xffffu];
#pragma unroll
    for (int b = 0; b < 32; ++b) cnt[b] += (int)((x >> b) & 1u);
  }
#pragma unroll
  for (int b = 0; b < 32; ++b) atomicAdd(&s_cnt[b], cnt[b]);
  __syncthreads();
  if (tid < 32) {
    int d = w * 32 + tid;
    if (d < DIM) enc[d] = (float)(K - 2 * s_cnt[tid]);
  }
}

// ---------- 8. out[c] = enc . Wc[c] ----------
__global__ __launch_bounds__(256) void out_kernel(const float* __restrict__ Wc,
                                                  char* __restrict__ ws,
                                                  float* __restrict__ out) {
  const float* enc = (const float*)(ws + WS_ENC);
  __shared__ float red[4];
  int c = blockIdx.x;
  float s = 0.f;
  for (int d = threadIdx.x; d < DIM; d += 256) s += enc[d] * Wc[c * DIM + d];
  for (int o = 32; o > 0; o >>= 1) s += __shfl_down(s, o, 64);
  if ((threadIdx.x & 63) == 0) red[threadIdx.x >> 6] = s;
  __syncthreads();
  if (threadIdx.x == 0) out[c] = red[0] + red[1] + red[2] + red[3];
}

extern "C" void kernel_launch(void* const* d_in, const int* in_sizes, int n_in,
                              void* d_out, int out_size, void* d_ws, size_t ws_size,
                              hipStream_t stream) {
  const int* eidx = (const int*)d_in[0];        // edge_index int32 [2, 8192]
  const float* Wn = (const float*)d_in[1];      // node_ids_weight f32 [2000, 10000]
  const float* Wc = (const float*)d_in[2];      // classify_weight f32 [10, 10000]
  float* out = (float*)d_out;
  char* ws = (char*)d_ws;

  hipMemsetAsync(ws, 0, WS_ZERO_BYTES, stream);
  hipMemsetAsync(ws + WS_HASH, 0xFF, HASH_SZ * 4, stream);

  // pack is independent of the graph pipeline; issue it first
  pack_kernel<<<(NN * WORDS + 255) / 256, 256, 0, stream>>>(Wn, (unsigned int*)(ws + WS_PACK));

  count_kernel<<<NCHUNK, CPE, 0, stream>>>(eidx, (int*)(ws + WS_DEG), (int*)(ws + WS_CHUNK));
  scan_kernel<<<1, 1024, 0, stream>>>((int*)(ws + WS_BASE), (int*)(ws + WS_CHUNK));
  fill_kernel<<<NCHUNK, CPE, 0, stream>>>(eidx, (const int*)(ws + WS_CHUNK),
                                          (unsigned short*)(ws + WS_CCOL));
  pr_kernel<<<1, 1024, 0, stream>>>(ws);
  rank_kernel<<<(NN + 255) / 256, 256, 0, stream>>>(ws);
  dedup_kernel<<<NE / 256, 256, 0, stream>>>(eidx, ws);
  encpop_kernel<<<WORDS, 256, 0, stream>>>(ws);
  out_kernel<<<NCLS, 256, 0, stream>>>(Wc, ws, out);
}

// Round 3
// 185.676 us; speedup vs baseline: 1.7183x; 1.3836x over previous
//
#include <hip/hip_runtime.h>
#include <hip/hip_bf16.h>

#define NN 2000
#define NE 8192
#define DIM 10000
#define NCLS 10
#define NCHUNK 32          // edge chunks for stable CSR build
#define CPE 256            // edges per chunk
#define HASH_SZ 32768
#define WORDS 313          // ceil(10000/32) packed sign words per node
#define ECH 8              // edge-chunk split for encpop grid.y

// ---- workspace layout (byte offsets) ----
#define WS_K       0                      // int        (distinct-edge counter)
#define WS_ENC     64                     // int[10016] per-dim xor-bit counts
#define WS_DEG     40128                  // int[2000]  (in-degree of col side)
#define WS_BASE    48128                  // int[2001]  (CSR row starts)
#define WS_CHUNK   56192                  // int[32*2000] per-chunk per-node counts -> offsets
#define WS_CCOL    312192                 // u16[8192]  CSR col values (edge-index order per node)
#define WS_V       328576                 // f32[2000]  pagerank result
#define WS_RANK    336576                 // int[2000]  stable rank of each node
#define WS_PAIRS   344576                 // u32[8192]  packed (rank[a]<<16)|rank[b] per distinct edge
#define WS_HASH    377344                 // int[32768] hash set
#define WS_PACK    508416                 // u32[313*2000] packed sign bits, layout [word][node]
#define WS_ZERO_BYTES 312192              // zero [0, WS_CCOL)

// ---------- 1. counts: deg (col side) + per-chunk per-node row counts ----------
__global__ __launch_bounds__(256) void count_kernel(const int* __restrict__ eidx,
                                                    int* __restrict__ deg,
                                                    int* __restrict__ chunk) {
  int e = blockIdx.x * CPE + threadIdx.x;
  int r = eidx[e];
  int c = eidx[NE + e];
  atomicAdd(&deg[c], 1);
  atomicAdd(&chunk[blockIdx.x * NN + r], 1);
}

// ---------- 2. scan: node totals -> exclusive base; chunk counts -> chunk offsets ----------
__global__ __launch_bounds__(1024) void scan_kernel(int* __restrict__ base,
                                                    int* __restrict__ chunk) {
  __shared__ int s[2048];
  int tid = threadIdx.x;
  int n0 = tid, n1 = tid + 1024;
  int t0 = 0, t1 = 0;
  for (int b = 0; b < NCHUNK; ++b) t0 += chunk[b * NN + n0];
  if (n1 < NN) for (int b = 0; b < NCHUNK; ++b) t1 += chunk[b * NN + n1];
  s[n0] = t0;
  s[n1] = (n1 < NN) ? t1 : 0;
  __syncthreads();
  for (int dstep = 1; dstep < 2048; dstep <<= 1) {
    int v0 = (n0 >= dstep) ? s[n0 - dstep] : 0;
    int v1 = (n1 >= dstep) ? s[n1 - dstep] : 0;
    __syncthreads();
    s[n0] += v0;
    s[n1] += v1;
    __syncthreads();
  }
  if (tid == 0) base[0] = 0;
  for (int n = tid; n < NN; n += 1024) base[n + 1] = s[n];
  // in-place turn chunk counts into chunk start offsets (stable: chunk-major = edge order)
  for (int n = tid; n < NN; n += 1024) {
    int run = (n == 0) ? 0 : s[n - 1];
    for (int b = 0; b < NCHUNK; ++b) {
      int t = chunk[b * NN + n];
      chunk[b * NN + n] = run;
      run += t;
    }
  }
}

// ---------- 3. stable fill: CSR col list in edge-index order per node ----------
__global__ __launch_bounds__(256) void fill_kernel(const int* __restrict__ eidx,
                                                   const int* __restrict__ chunk,
                                                   unsigned short* __restrict__ ccol) {
  __shared__ int s_rows[CPE];
  int tid = threadIdx.x;
  int e = blockIdx.x * CPE + tid;
  int r = eidx[e];
  int c = eidx[NE + e];
  s_rows[tid] = r;
  __syncthreads();
  int cntb = 0;
  for (int j = 0; j < tid; ++j) cntb += (s_rows[j] == r) ? 1 : 0;
  int slot = chunk[blockIdx.x * NN + r] + cntb;
  ccol[slot] = (unsigned short)c;
}

// ---------- 4. pagerank power iteration (single block, bit-exact f32, edge order) ----------
__global__ __launch_bounds__(1024) void pr_kernel(char* __restrict__ ws) {
  const int* deg_g = (const int*)(ws + WS_DEG);
  const int* base_g = (const int*)(ws + WS_BASE);
  const unsigned short* ccol_g = (const unsigned short*)(ws + WS_CCOL);
  float* vout = (float*)(ws + WS_V);

  __shared__ unsigned short s_ccol[NE];   // 16384 B
  __shared__ float s_val[NN];             // 8000 B: 0.85f/deg[c]
  __shared__ int s_base[NN + 1];          // 8004 B
  __shared__ float s_v[NN];               // 8000 B
  __shared__ float s_red[2][16];

  int tid = threadIdx.x;
  int wid = tid >> 6, lane = tid & 63;
  for (int i = tid; i < NE; i += 1024) s_ccol[i] = ccol_g[i];
  for (int i = tid; i < NN; i += 1024) s_val[i] = 0.85f / (float)deg_g[i]; // inf if deg==0: never used
  for (int i = tid; i <= NN; i += 1024) s_base[i] = base_g[i];
  const float p = 0.0005f;                 // f32(1.0/2000)
  const float addv = 0.0005f * 0.15f;      // p * f32(1.0-0.85)
  for (int i = tid; i < NN; i += 1024) s_v[i] = p;
  __syncthreads();

  float err = __builtin_inff();
  int it = 0;
  int pb = 0;
  while (it < 100 && err >= 0.002f) {
    float vn0 = 0.f, vn1 = 0.f, ep = 0.f;
    {
      int n = tid;
      int s0 = s_base[n], e2 = s_base[n + 1];
      float sum = 0.f;
      for (int k = s0; k < e2; ++k) {
        int c = s_ccol[k];
        sum = __fadd_rn(sum, __fmul_rn(s_val[c], s_v[c]));
      }
      vn0 = __fadd_rn(sum, addv);
      ep += fabsf(__fsub_rn(vn0, s_v[n]));
    }
    if (tid + 1024 < NN) {
      int n = tid + 1024;
      int s0 = s_base[n], e2 = s_base[n + 1];
      float sum = 0.f;
      for (int k = s0; k < e2; ++k) {
        int c = s_ccol[k];
        sum = __fadd_rn(sum, __fmul_rn(s_val[c], s_v[c]));
      }
      vn1 = __fadd_rn(sum, addv);
      ep += fabsf(__fsub_rn(vn1, s_v[tid + 1024]));
    }
    for (int o = 32; o > 0; o >>= 1) ep += __shfl_down(ep, o, 64);
    if (lane == 0) s_red[pb][wid] = ep;
    __syncthreads();            // old s_v reads done; s_red[pb] visible
    s_v[tid] = vn0;
    if (tid + 1024 < NN) s_v[tid + 1024] = vn1;
    float t = 0.f;
#pragma unroll
    for (int w2 = 0; w2 < 16; ++w2) t += s_red[pb][w2];   // same order as before: bit-identical err
    err = t;
    pb ^= 1;
    ++it;
    __syncthreads();            // s_v writes visible for next iteration
  }
  for (int i = tid; i < NN; i += 1024) vout[i] = s_v[i];
}

// ---------- 5. stable rank (matches stable argsort, ties by index) ----------
__global__ __launch_bounds__(256) void rank_kernel(char* __restrict__ ws) {
  const float* v = (const float*)(ws + WS_V);
  int* rnk = (int*)(ws + WS_RANK);
  int i = blockIdx.x * 256 + threadIdx.x;
  if (i >= NN) return;
  float vi = v[i];
  int r = 0;
  for (int j = 0; j < NN; ++j) {
    float vj = v[j];
    r += ((vj < vi) || (vj == vi && j < i)) ? 1 : 0;
  }
  rnk[i] = r;
}

// ---------- 6. dedup undirected edges via hash set; emit packed ranked pairs ----------
__global__ __launch_bounds__(256) void dedup_kernel(const int* __restrict__ eidx,
                                                    char* __restrict__ ws) {
  int* hash = (int*)(ws + WS_HASH);
  unsigned int* pairs = (unsigned int*)(ws + WS_PAIRS);
  int* Kp = (int*)(ws + WS_K);
  const int* rnk = (const int*)(ws + WS_RANK);
  int e = blockIdx.x * 256 + threadIdx.x;
  int r = eidx[e], c = eidx[NE + e];
  int a = min(r, c), b = max(r, c);
  int key = a * NN + b;
  unsigned int h = ((unsigned int)key * 2654435761u) >> 17;
  for (;;) {
    h &= (HASH_SZ - 1);
    int old = atomicCAS(&hash[h], -1, key);
    if (old == -1) {                       // this edge owns the distinct key
      int idx = atomicAdd(Kp, 1);
      pairs[idx] = ((unsigned int)rnk[a] << 16) | (unsigned int)rnk[b];
      return;
    }
    if (old == key) return;                // duplicate
    ++h;
  }
}

// ---------- 7a. pack sign bits: packed[word][node]; node-major threads -> coalesced writes ----------
__global__ __launch_bounds__(256) void pack_kernel(const float* __restrict__ W,
                                                   unsigned int* __restrict__ packed) {
  int t = blockIdx.x * 256 + threadIdx.x;
  if (t >= NN * WORDS) return;
  int w = t / NN;
  int node = t - w * NN;               // consecutive threads -> consecutive nodes, same word
  int d0 = w * 32;
  const float* p = W + (size_t)node * DIM + d0;   // 128B-aligned per-lane chunk
  unsigned int m = 0;
  if (d0 + 32 <= DIM) {
#pragma unroll
    for (int q = 0; q < 8; ++q) {
      float4 v4 = *reinterpret_cast<const float4*>(p + q * 4);
      m |= (__float_as_uint(v4.x) >> 31) << (q * 4);
      m |= (__float_as_uint(v4.y) >> 31) << (q * 4 + 1);
      m |= (__float_as_uint(v4.z) >> 31) << (q * 4 + 2);
      m |= (__float_as_uint(v4.w) >> 31) << (q * 4 + 3);
    }
  } else {
    for (int j = 0; j < DIM - d0; ++j) m |= (__float_as_uint(p[j]) >> 31) << j;
  }
  packed[(size_t)w * NN + node] = m;   // coalesced
}

// ---------- 7b. per-dim xor-bit counts via ballot+popcount, edge-split grid ----------
__global__ __launch_bounds__(256) void encpop_kernel(char* __restrict__ ws) {
  const unsigned int* packed = (const unsigned int*)(ws + WS_PACK);
  const unsigned int* pairs = (const unsigned int*)(ws + WS_PAIRS);
  const int* Kp = (const int*)(ws + WS_K);
  int* enc_int = (int*)(ws + WS_ENC);
  __shared__ unsigned int s_col[NN];   // this word's bits for all 2000 rows (by rank)
  __shared__ int s_part[4][32];
  int w = blockIdx.x;
  int tid = threadIdx.x;
  int wid = tid >> 6, lane = tid & 63;
  for (int i = tid; i < NN; i += 256) s_col[i] = packed[(size_t)w * NN + i];
  __syncthreads();
  int K = *Kp;
  const int per = NE / ECH;            // 1024
  int e0 = blockIdx.y * per;
  int cnt[32];
#pragma unroll
  for (int b = 0; b < 32; ++b) cnt[b] = 0;
  for (int e = e0 + tid; e < e0 + per; e += 256) {   // uniform trip count: ballot-safe
    unsigned int x = 0;
    if (e < K) {
      unsigned int pk = pairs[e];
      x = s_col[pk >> 16] ^ s_col[pk & 0xffffu];
    }
#pragma unroll
    for (int b = 0; b < 32; ++b)
      cnt[b] += (int)__popcll(__ballot(x & (1u << b)));   // uniform per wave
  }
  if (lane == 0) {
#pragma unroll
    for (int b = 0; b < 32; ++b) s_part[wid][b] = cnt[b];
  }
  __syncthreads();
  if (tid < 32) {
    int tot = s_part[0][tid] + s_part[1][tid] + s_part[2][tid] + s_part[3][tid];
    if (tot) atomicAdd(&enc_int[w * 32 + tid], tot);   // exact integer accumulation
  }
}

// ---------- 8. out[c] = sum_d (K - 2*cnt[d]) * Wc[c][d] ----------
__global__ __launch_bounds__(256) void out_kernel(const float* __restrict__ Wc,
                                                  char* __restrict__ ws,
                                                  float* __restrict__ out) {
  const int* enc_int = (const int*)(ws + WS_ENC);
  int K = *(const int*)(ws + WS_K);
  __shared__ float red[4];
  int c = blockIdx.x;
  float s = 0.f;
  for (int d = threadIdx.x; d < DIM; d += 256)
    s += (float)(K - 2 * enc_int[d]) * Wc[c * DIM + d];
  for (int o = 32; o > 0; o >>= 1) s += __shfl_down(s, o, 64);
  if ((threadIdx.x & 63) == 0) red[threadIdx.x >> 6] = s;
  __syncthreads();
  if (threadIdx.x == 0) out[c] = red[0] + red[1] + red[2] + red[3];
}

extern "C" void kernel_launch(void* const* d_in, const int* in_sizes, int n_in,
                              void* d_out, int out_size, void* d_ws, size_t ws_size,
                              hipStream_t stream) {
  const int* eidx = (const int*)d_in[0];        // edge_index int32 [2, 8192]
  const float* Wn = (const float*)d_in[1];      // node_ids_weight f32 [2000, 10000]
  const float* Wc = (const float*)d_in[2];      // classify_weight f32 [10, 10000]
  float* out = (float*)d_out;
  char* ws = (char*)d_ws;

  hipMemsetAsync(ws, 0, WS_ZERO_BYTES, stream);
  hipMemsetAsync(ws + WS_HASH, 0xFF, HASH_SZ * 4, stream);

  // pack is independent of the graph pipeline; issue it first
  pack_kernel<<<(NN * WORDS + 255) / 256, 256, 0, stream>>>(Wn, (unsigned int*)(ws + WS_PACK));

  count_kernel<<<NCHUNK, CPE, 0, stream>>>(eidx, (int*)(ws + WS_DEG), (int*)(ws + WS_CHUNK));
  scan_kernel<<<1, 1024, 0, stream>>>((int*)(ws + WS_BASE), (int*)(ws + WS_CHUNK));
  fill_kernel<<<NCHUNK, CPE, 0, stream>>>(eidx, (const int*)(ws + WS_CHUNK),
                                          (unsigned short*)(ws + WS_CCOL));
  pr_kernel<<<1, 1024, 0, stream>>>(ws);
  rank_kernel<<<(NN + 255) / 256, 256, 0, stream>>>(ws);
  dedup_kernel<<<NE / 256, 256, 0, stream>>>(eidx, ws);
  encpop_kernel<<<dim3(WORDS, ECH), 256, 0, stream>>>(ws);
  out_kernel<<<NCLS, 256, 0, stream>>>(Wc, ws, out);
}

// Round 4
// 125.567 us; speedup vs baseline: 2.5409x; 1.4787x over previous
//
#include <hip/hip_runtime.h>
#include <hip/hip_bf16.h>

#define NN 2000
#define NE 8192
#define DIM 10000
#define NCLS 10
#define NCHUNK 32          // edge chunks for stable CSR build
#define CPE 256            // edges per chunk
#define HASH_SZ 32768
#define WORDS 313          // ceil(10000/32) packed sign words per node
#define ECH 8              // edge-chunk split for encpop grid.y
#define RBLK 64            // i-rows per rank block

// ---- workspace layout (byte offsets) ----
#define WS_K       0                      // int        (distinct-edge counter)
#define WS_ENC     64                     // int[10016] per-dim xor-bit counts
#define WS_DEG     40128                  // int[2000]  (in-degree of col side)
#define WS_BASE    48128                  // int[2001]  (CSR row starts)
#define WS_CHUNK   56192                  // int[32*2000] per-chunk per-node counts -> offsets
#define WS_CCOL    312192                 // u16[8192]  CSR col values (edge-index order per node)
#define WS_V       328576                 // f32[2000]  pagerank result
#define WS_RANK    336576                 // int[2000]  stable rank of each node
#define WS_PAIRS   344576                 // u32[8192]  packed (rank[a]<<16)|rank[b] per distinct edge
#define WS_HASH    377344                 // int[32768] hash set
#define WS_PACK    508416                 // u32[313*2000] packed sign bits, layout [word][node]
#define WS_ZERO_BYTES 312192              // zero [0, WS_CCOL)

// ---------- 1. counts: deg (col side) + per-chunk per-node row counts ----------
__global__ __launch_bounds__(256) void count_kernel(const int* __restrict__ eidx,
                                                    int* __restrict__ deg,
                                                    int* __restrict__ chunk) {
  int e = blockIdx.x * CPE + threadIdx.x;
  int r = eidx[e];
  int c = eidx[NE + e];
  atomicAdd(&deg[c], 1);
  atomicAdd(&chunk[blockIdx.x * NN + r], 1);
}

// ---------- 2. scan: node totals -> exclusive base; chunk counts -> chunk offsets ----------
__global__ __launch_bounds__(1024) void scan_kernel(int* __restrict__ base,
                                                    int* __restrict__ chunk) {
  __shared__ int s[2048];
  int tid = threadIdx.x;
  int n0 = tid, n1 = tid + 1024;
  int t0 = 0, t1 = 0;
  for (int b = 0; b < NCHUNK; ++b) t0 += chunk[b * NN + n0];
  if (n1 < NN) for (int b = 0; b < NCHUNK; ++b) t1 += chunk[b * NN + n1];
  s[n0] = t0;
  s[n1] = (n1 < NN) ? t1 : 0;
  __syncthreads();
  for (int dstep = 1; dstep < 2048; dstep <<= 1) {
    int v0 = (n0 >= dstep) ? s[n0 - dstep] : 0;
    int v1 = (n1 >= dstep) ? s[n1 - dstep] : 0;
    __syncthreads();
    s[n0] += v0;
    s[n1] += v1;
    __syncthreads();
  }
  if (tid == 0) base[0] = 0;
  for (int n = tid; n < NN; n += 1024) base[n + 1] = s[n];
  // in-place turn chunk counts into chunk start offsets (stable: chunk-major = edge order)
  for (int n = tid; n < NN; n += 1024) {
    int run = (n == 0) ? 0 : s[n - 1];
    for (int b = 0; b < NCHUNK; ++b) {
      int t = chunk[b * NN + n];
      chunk[b * NN + n] = run;
      run += t;
    }
  }
}

// ---------- 3. stable fill: CSR col list in edge-index order per node ----------
__global__ __launch_bounds__(256) void fill_kernel(const int* __restrict__ eidx,
                                                   const int* __restrict__ chunk,
                                                   unsigned short* __restrict__ ccol) {
  __shared__ int s_rows[CPE];
  int tid = threadIdx.x;
  int e = blockIdx.x * CPE + tid;
  int r = eidx[e];
  int c = eidx[NE + e];
  s_rows[tid] = r;
  __syncthreads();
  int cntb = 0;
  for (int j = 0; j < tid; ++j) cntb += (s_rows[j] == r) ? 1 : 0;
  int slot = chunk[blockIdx.x * NN + r] + cntb;
  ccol[slot] = (unsigned short)c;
}

// ---------- 4. pagerank power iteration (single block, bit-exact f32, edge order) ----------
__global__ __launch_bounds__(1024) void pr_kernel(char* __restrict__ ws) {
  const int* deg_g = (const int*)(ws + WS_DEG);
  const int* base_g = (const int*)(ws + WS_BASE);
  const unsigned short* ccol_g = (const unsigned short*)(ws + WS_CCOL);
  float* vout = (float*)(ws + WS_V);

  __shared__ unsigned short s_ccol[NE];   // 16384 B
  __shared__ float s_val[NN];             // 8000 B: 0.85f/deg[c]
  __shared__ int s_base[NN + 1];          // 8004 B
  __shared__ float s_v[NN];               // 8000 B
  __shared__ float s_red[2][16];

  int tid = threadIdx.x;
  int wid = tid >> 6, lane = tid & 63;
  for (int i = tid; i < NE; i += 1024) s_ccol[i] = ccol_g[i];
  for (int i = tid; i < NN; i += 1024) s_val[i] = 0.85f / (float)deg_g[i]; // inf if deg==0: never used
  for (int i = tid; i <= NN; i += 1024) s_base[i] = base_g[i];
  const float p = 0.0005f;                 // f32(1.0/2000)
  const float addv = 0.0005f * 0.15f;      // p * f32(1.0-0.85)
  for (int i = tid; i < NN; i += 1024) s_v[i] = p;
  __syncthreads();

  float err = __builtin_inff();
  int it = 0;
  int pb = 0;
  while (it < 100 && err >= 0.002f) {
    float vn0 = 0.f, vn1 = 0.f, ep = 0.f;
    {
      int n = tid;
      int s0 = s_base[n], e2 = s_base[n + 1];
      float sum = 0.f;
      for (int k = s0; k < e2; ++k) {
        int c = s_ccol[k];
        sum = __fadd_rn(sum, __fmul_rn(s_val[c], s_v[c]));
      }
      vn0 = __fadd_rn(sum, addv);
      ep += fabsf(__fsub_rn(vn0, s_v[n]));
    }
    if (tid + 1024 < NN) {
      int n = tid + 1024;
      int s0 = s_base[n], e2 = s_base[n + 1];
      float sum = 0.f;
      for (int k = s0; k < e2; ++k) {
        int c = s_ccol[k];
        sum = __fadd_rn(sum, __fmul_rn(s_val[c], s_v[c]));
      }
      vn1 = __fadd_rn(sum, addv);
      ep += fabsf(__fsub_rn(vn1, s_v[tid + 1024]));
    }
    for (int o = 32; o > 0; o >>= 1) ep += __shfl_down(ep, o, 64);
    if (lane == 0) s_red[pb][wid] = ep;
    __syncthreads();            // old s_v reads done; s_red[pb] visible
    s_v[tid] = vn0;
    if (tid + 1024 < NN) s_v[tid + 1024] = vn1;
    float t = 0.f;
#pragma unroll
    for (int w2 = 0; w2 < 16; ++w2) t += s_red[pb][w2];   // same order as before: bit-identical err
    err = t;
    pb ^= 1;
    ++it;
    __syncthreads();            // s_v writes visible for next iteration
  }
  for (int i = tid; i < NN; i += 1024) vout[i] = s_v[i];
}

// ---------- 5. stable rank: LDS-staged, 4-way j-split, 32 blocks ----------
__global__ __launch_bounds__(256) void rank_kernel(char* __restrict__ ws) {
  const float* v = (const float*)(ws + WS_V);
  int* rnk = (int*)(ws + WS_RANK);
  __shared__ float s_v[NN];
  __shared__ int s_part[4][RBLK];
  int tid = threadIdx.x;
  for (int j = tid; j < NN; j += 256) s_v[j] = v[j];
  __syncthreads();
  int li = tid & (RBLK - 1);
  int seg = tid >> 6;                    // 0..3
  int i = blockIdx.x * RBLK + li;
  float vi = (i < NN) ? s_v[i] : 0.f;
  const int jper = NN / 4;               // 500
  int j0 = seg * jper, j1 = j0 + jper;
  int r = 0;
  for (int j = j0; j < j1; ++j) {
    float vj = s_v[j];                   // broadcast: conflict-free
    r += ((vj < vi) || (vj == vi && j < i)) ? 1 : 0;
  }
  s_part[seg][li] = r;
  __syncthreads();
  if (tid < RBLK) {
    int i2 = blockIdx.x * RBLK + tid;
    if (i2 < NN)
      rnk[i2] = s_part[0][tid] + s_part[1][tid] + s_part[2][tid] + s_part[3][tid];
  }
}

// ---------- 6. dedup undirected edges via hash set; emit packed ranked pairs ----------
__global__ __launch_bounds__(256) void dedup_kernel(const int* __restrict__ eidx,
                                                    char* __restrict__ ws) {
  int* hash = (int*)(ws + WS_HASH);
  unsigned int* pairs = (unsigned int*)(ws + WS_PAIRS);
  int* Kp = (int*)(ws + WS_K);
  const int* rnk = (const int*)(ws + WS_RANK);
  int e = blockIdx.x * 256 + threadIdx.x;
  int r = eidx[e], c = eidx[NE + e];
  int a = min(r, c), b = max(r, c);
  int key = a * NN + b;
  unsigned int h = ((unsigned int)key * 2654435761u) >> 17;
  for (;;) {
    h &= (HASH_SZ - 1);
    int old = atomicCAS(&hash[h], -1, key);
    if (old == -1) {                       // this edge owns the distinct key
      int idx = atomicAdd(Kp, 1);
      pairs[idx] = ((unsigned int)rnk[a] << 16) | (unsigned int)rnk[b];
      return;
    }
    if (old == key) return;                // duplicate
    ++h;
  }
}

// ---------- 7a. pack sign bits: packed[word][node]; node-major threads -> coalesced writes ----------
__global__ __launch_bounds__(256) void pack_kernel(const float* __restrict__ W,
                                                   unsigned int* __restrict__ packed) {
  int t = blockIdx.x * 256 + threadIdx.x;
  if (t >= NN * WORDS) return;
  int w = t / NN;
  int node = t - w * NN;               // consecutive threads -> consecutive nodes, same word
  int d0 = w * 32;
  const float* p = W + (size_t)node * DIM + d0;   // 128B-aligned per-lane chunk
  unsigned int m = 0;
  if (d0 + 32 <= DIM) {
#pragma unroll
    for (int q = 0; q < 8; ++q) {
      float4 v4 = *reinterpret_cast<const float4*>(p + q * 4);
      m |= (__float_as_uint(v4.x) >> 31) << (q * 4);
      m |= (__float_as_uint(v4.y) >> 31) << (q * 4 + 1);
      m |= (__float_as_uint(v4.z) >> 31) << (q * 4 + 2);
      m |= (__float_as_uint(v4.w) >> 31) << (q * 4 + 3);
    }
  } else {
    for (int j = 0; j < DIM - d0; ++j) m |= (__float_as_uint(p[j]) >> 31) << j;
  }
  packed[(size_t)w * NN + node] = m;   // coalesced
}

// ---------- 7b. per-dim xor-bit counts via ballot+popcount, edge-split grid ----------
__global__ __launch_bounds__(256) void encpop_kernel(char* __restrict__ ws) {
  const unsigned int* packed = (const unsigned int*)(ws + WS_PACK);
  const unsigned int* pairs = (const unsigned int*)(ws + WS_PAIRS);
  const int* Kp = (const int*)(ws + WS_K);
  int* enc_int = (int*)(ws + WS_ENC);
  __shared__ unsigned int s_col[NN];   // this word's bits for all 2000 rows (by rank)
  __shared__ int s_part[4][32];
  int w = blockIdx.x;
  int tid = threadIdx.x;
  int wid = tid >> 6, lane = tid & 63;
  for (int i = tid; i < NN; i += 256) s_col[i] = packed[(size_t)w * NN + i];
  __syncthreads();
  int K = *Kp;
  const int per = NE / ECH;            // 1024
  int e0 = blockIdx.y * per;
  int cnt[32];
#pragma unroll
  for (int b = 0; b < 32; ++b) cnt[b] = 0;
  for (int e = e0 + tid; e < e0 + per; e += 256) {   // uniform trip count: ballot-safe
    unsigned int x = 0;
    if (e < K) {
      unsigned int pk = pairs[e];
      x = s_col[pk >> 16] ^ s_col[pk & 0xffffu];
    }
#pragma unroll
    for (int b = 0; b < 32; ++b)
      cnt[b] += (int)__popcll(__ballot(x & (1u << b)));   // uniform per wave
  }
  if (lane == 0) {
#pragma unroll
    for (int b = 0; b < 32; ++b) s_part[wid][b] = cnt[b];
  }
  __syncthreads();
  if (tid < 32) {
    int tot = s_part[0][tid] + s_part[1][tid] + s_part[2][tid] + s_part[3][tid];
    if (tot) atomicAdd(&enc_int[w * 32 + tid], tot);   // exact integer accumulation
  }
}

// ---------- 8. out[c] = sum_d (K - 2*cnt[d]) * Wc[c][d] ----------
__global__ __launch_bounds__(256) void out_kernel(const float* __restrict__ Wc,
                                                  char* __restrict__ ws,
                                                  float* __restrict__ out) {
  const int* enc_int = (const int*)(ws + WS_ENC);
  int K = *(const int*)(ws + WS_K);
  __shared__ float red[4];
  int c = blockIdx.x;
  float s = 0.f;
  for (int d = threadIdx.x; d < DIM; d += 256)
    s += (float)(K - 2 * enc_int[d]) * Wc[c * DIM + d];
  for (int o = 32; o > 0; o >>= 1) s += __shfl_down(s, o, 64);
  if ((threadIdx.x & 63) == 0) red[threadIdx.x >> 6] = s;
  __syncthreads();
  if (threadIdx.x == 0) out[c] = red[0] + red[1] + red[2] + red[3];
}

extern "C" void kernel_launch(void* const* d_in, const int* in_sizes, int n_in,
                              void* d_out, int out_size, void* d_ws, size_t ws_size,
                              hipStream_t stream) {
  const int* eidx = (const int*)d_in[0];        // edge_index int32 [2, 8192]
  const float* Wn = (const float*)d_in[1];      // node_ids_weight f32 [2000, 10000]
  const float* Wc = (const float*)d_in[2];      // classify_weight f32 [10, 10000]
  float* out = (float*)d_out;
  char* ws = (char*)d_ws;

  hipMemsetAsync(ws, 0, WS_ZERO_BYTES, stream);
  hipMemsetAsync(ws + WS_HASH, 0xFF, HASH_SZ * 4, stream);

  // pack is independent of the graph pipeline; issue it first
  pack_kernel<<<(NN * WORDS + 255) / 256, 256, 0, stream>>>(Wn, (unsigned int*)(ws + WS_PACK));

  count_kernel<<<NCHUNK, CPE, 0, stream>>>(eidx, (int*)(ws + WS_DEG), (int*)(ws + WS_CHUNK));
  scan_kernel<<<1, 1024, 0, stream>>>((int*)(ws + WS_BASE), (int*)(ws + WS_CHUNK));
  fill_kernel<<<NCHUNK, CPE, 0, stream>>>(eidx, (const int*)(ws + WS_CHUNK),
                                          (unsigned short*)(ws + WS_CCOL));
  pr_kernel<<<1, 1024, 0, stream>>>(ws);
  rank_kernel<<<(NN + RBLK - 1) / RBLK, 256, 0, stream>>>(ws);
  dedup_kernel<<<NE / 256, 256, 0, stream>>>(eidx, ws);
  encpop_kernel<<<dim3(WORDS, ECH), 256, 0, stream>>>(ws);
  out_kernel<<<NCLS, 256, 0, stream>>>(Wc, ws, out);
}

// Round 5
// 122.811 us; speedup vs baseline: 2.5979x; 1.0224x over previous
//
#include <hip/hip_runtime.h>
#include <hip/hip_bf16.h>

#define NN 2000
#define NE 8192
#define DIM 10000
#define NCLS 10
#define NCHUNK 32          // edge chunks for stable CSR build
#define CPE 256            // edges per chunk
#define HASH_SZ 32768
#define WORDS 313          // ceil(10000/32) packed sign words per node
#define ECH 8              // edge-chunk split for encpop grid.y
#define RBLK 64            // i-rows per rank block

// ---- workspace layout (byte offsets) ----
#define WS_K       0                      // int        (distinct-edge counter)
#define WS_ENC     64                     // int[10016] per-dim xor-bit counts
#define WS_DEG     40128                  // int[2000]  (in-degree of col side)
#define WS_BASE    48128                  // int[2001]  (CSR row starts)
#define WS_CHUNK   56192                  // int[32*2000] per-chunk per-node counts -> offsets
#define WS_CCOL    312192                 // u16[8192]  CSR col values (edge-index order per node)
#define WS_V       328576                 // f32[2000]  pagerank result
#define WS_RANK    336576                 // int[2000]  stable rank of each node
#define WS_PAIRS   344576                 // u32[8192]  packed (rank[a]<<16)|rank[b] per distinct edge
#define WS_HASH    377344                 // int[32768] hash set
#define WS_PACK    508416                 // u32[313*2000] packed sign bits, layout [word][node]
#define WS_ZERO_BYTES 312192              // zero [0, WS_CCOL)

#define ZERO_VEC (WS_ZERO_BYTES / 16)     // 19512 uint4 zero stores
#define HASH_VEC (HASH_SZ * 4 / 16)       // 8192  uint4 0xFF stores
#define INIT_TOT (ZERO_VEC + HASH_VEC)    // 27704

// ---------- 0. init: replaces two hipMemsetAsync (each cost ~48us as fillBuffer) ----------
__global__ __launch_bounds__(256) void init_kernel(char* __restrict__ ws) {
  int t = blockIdx.x * 256 + threadIdx.x;
  if (t < ZERO_VEC) {
    reinterpret_cast<uint4*>(ws)[t] = make_uint4(0u, 0u, 0u, 0u);
  } else if (t < INIT_TOT) {
    reinterpret_cast<uint4*>(ws + WS_HASH)[t - ZERO_VEC] =
        make_uint4(0xFFFFFFFFu, 0xFFFFFFFFu, 0xFFFFFFFFu, 0xFFFFFFFFu);
  }
}

// ---------- 1. counts: deg (col side) + per-chunk per-node row counts ----------
__global__ __launch_bounds__(256) void count_kernel(const int* __restrict__ eidx,
                                                    int* __restrict__ deg,
                                                    int* __restrict__ chunk) {
  int e = blockIdx.x * CPE + threadIdx.x;
  int r = eidx[e];
  int c = eidx[NE + e];
  atomicAdd(&deg[c], 1);
  atomicAdd(&chunk[blockIdx.x * NN + r], 1);
}

// ---------- 2. scan: node totals -> exclusive base; chunk counts -> chunk offsets ----------
__global__ __launch_bounds__(1024) void scan_kernel(int* __restrict__ base,
                                                    int* __restrict__ chunk) {
  __shared__ int s[2048];
  int tid = threadIdx.x;
  int n0 = tid, n1 = tid + 1024;
  int t0 = 0, t1 = 0;
  for (int b = 0; b < NCHUNK; ++b) t0 += chunk[b * NN + n0];
  if (n1 < NN) for (int b = 0; b < NCHUNK; ++b) t1 += chunk[b * NN + n1];
  s[n0] = t0;
  s[n1] = (n1 < NN) ? t1 : 0;
  __syncthreads();
  for (int dstep = 1; dstep < 2048; dstep <<= 1) {
    int v0 = (n0 >= dstep) ? s[n0 - dstep] : 0;
    int v1 = (n1 >= dstep) ? s[n1 - dstep] : 0;
    __syncthreads();
    s[n0] += v0;
    s[n1] += v1;
    __syncthreads();
  }
  if (tid == 0) base[0] = 0;
  for (int n = tid; n < NN; n += 1024) base[n + 1] = s[n];
  // in-place turn chunk counts into chunk start offsets (stable: chunk-major = edge order)
  for (int n = tid; n < NN; n += 1024) {
    int run = (n == 0) ? 0 : s[n - 1];
    for (int b = 0; b < NCHUNK; ++b) {
      int t = chunk[b * NN + n];
      chunk[b * NN + n] = run;
      run += t;
    }
  }
}

// ---------- 3. stable fill: CSR col list in edge-index order per node ----------
__global__ __launch_bounds__(256) void fill_kernel(const int* __restrict__ eidx,
                                                   const int* __restrict__ chunk,
                                                   unsigned short* __restrict__ ccol) {
  __shared__ int s_rows[CPE];
  int tid = threadIdx.x;
  int e = blockIdx.x * CPE + tid;
  int r = eidx[e];
  int c = eidx[NE + e];
  s_rows[tid] = r;
  __syncthreads();
  int cntb = 0;
  for (int j = 0; j < tid; ++j) cntb += (s_rows[j] == r) ? 1 : 0;
  int slot = chunk[blockIdx.x * NN + r] + cntb;
  ccol[slot] = (unsigned short)c;
}

// ---------- 4. pagerank power iteration (single block, bit-exact f32, edge order) ----------
__global__ __launch_bounds__(1024) void pr_kernel(char* __restrict__ ws) {
  const int* deg_g = (const int*)(ws + WS_DEG);
  const int* base_g = (const int*)(ws + WS_BASE);
  const unsigned short* ccol_g = (const unsigned short*)(ws + WS_CCOL);
  float* vout = (float*)(ws + WS_V);

  __shared__ unsigned short s_ccol[NE];   // 16384 B
  __shared__ float s_val[NN];             // 8000 B: 0.85f/deg[c]
  __shared__ int s_base[NN + 1];          // 8004 B
  __shared__ float s_v[NN];               // 8000 B
  __shared__ float s_red[2][16];

  int tid = threadIdx.x;
  int wid = tid >> 6, lane = tid & 63;
  for (int i = tid; i < NE; i += 1024) s_ccol[i] = ccol_g[i];
  for (int i = tid; i < NN; i += 1024) s_val[i] = 0.85f / (float)deg_g[i]; // inf if deg==0: never used
  for (int i = tid; i <= NN; i += 1024) s_base[i] = base_g[i];
  const float p = 0.0005f;                 // f32(1.0/2000)
  const float addv = 0.0005f * 0.15f;      // p * f32(1.0-0.85)
  for (int i = tid; i < NN; i += 1024) s_v[i] = p;
  __syncthreads();

  float err = __builtin_inff();
  int it = 0;
  int pb = 0;
  while (it < 100 && err >= 0.002f) {
    float vn0 = 0.f, vn1 = 0.f, ep = 0.f;
    {
      int n = tid;
      int s0 = s_base[n], e2 = s_base[n + 1];
      float sum = 0.f;
      for (int k = s0; k < e2; ++k) {
        int c = s_ccol[k];
        sum = __fadd_rn(sum, __fmul_rn(s_val[c], s_v[c]));
      }
      vn0 = __fadd_rn(sum, addv);
      ep += fabsf(__fsub_rn(vn0, s_v[n]));
    }
    if (tid + 1024 < NN) {
      int n = tid + 1024;
      int s0 = s_base[n], e2 = s_base[n + 1];
      float sum = 0.f;
      for (int k = s0; k < e2; ++k) {
        int c = s_ccol[k];
        sum = __fadd_rn(sum, __fmul_rn(s_val[c], s_v[c]));
      }
      vn1 = __fadd_rn(sum, addv);
      ep += fabsf(__fsub_rn(vn1, s_v[tid + 1024]));
    }
    for (int o = 32; o > 0; o >>= 1) ep += __shfl_down(ep, o, 64);
    if (lane == 0) s_red[pb][wid] = ep;
    __syncthreads();            // old s_v reads done; s_red[pb] visible
    s_v[tid] = vn0;
    if (tid + 1024 < NN) s_v[tid + 1024] = vn1;
    float t = 0.f;
#pragma unroll
    for (int w2 = 0; w2 < 16; ++w2) t += s_red[pb][w2];   // same order as before: bit-identical err
    err = t;
    pb ^= 1;
    ++it;
    __syncthreads();            // s_v writes visible for next iteration
  }
  for (int i = tid; i < NN; i += 1024) vout[i] = s_v[i];
}

// ---------- 5. stable rank: LDS-staged, 4-way j-split, 32 blocks ----------
__global__ __launch_bounds__(256) void rank_kernel(char* __restrict__ ws) {
  const float* v = (const float*)(ws + WS_V);
  int* rnk = (int*)(ws + WS_RANK);
  __shared__ float s_v[NN];
  __shared__ int s_part[4][RBLK];
  int tid = threadIdx.x;
  for (int j = tid; j < NN; j += 256) s_v[j] = v[j];
  __syncthreads();
  int li = tid & (RBLK - 1);
  int seg = tid >> 6;                    // 0..3
  int i = blockIdx.x * RBLK + li;
  float vi = (i < NN) ? s_v[i] : 0.f;
  const int jper = NN / 4;               // 500
  int j0 = seg * jper, j1 = j0 + jper;
  int r = 0;
  for (int j = j0; j < j1; ++j) {
    float vj = s_v[j];                   // broadcast: conflict-free
    r += ((vj < vi) || (vj == vi && j < i)) ? 1 : 0;
  }
  s_part[seg][li] = r;
  __syncthreads();
  if (tid < RBLK) {
    int i2 = blockIdx.x * RBLK + tid;
    if (i2 < NN)
      rnk[i2] = s_part[0][tid] + s_part[1][tid] + s_part[2][tid] + s_part[3][tid];
  }
}

// ---------- 6. dedup undirected edges via hash set; emit packed ranked pairs ----------
__global__ __launch_bounds__(256) void dedup_kernel(const int* __restrict__ eidx,
                                                    char* __restrict__ ws) {
  int* hash = (int*)(ws + WS_HASH);
  unsigned int* pairs = (unsigned int*)(ws + WS_PAIRS);
  int* Kp = (int*)(ws + WS_K);
  const int* rnk = (const int*)(ws + WS_RANK);
  int e = blockIdx.x * 256 + threadIdx.x;
  int r = eidx[e], c = eidx[NE + e];
  int a = min(r, c), b = max(r, c);
  int key = a * NN + b;
  unsigned int h = ((unsigned int)key * 2654435761u) >> 17;
  for (;;) {
    h &= (HASH_SZ - 1);
    int old = atomicCAS(&hash[h], -1, key);
    if (old == -1) {                       // this edge owns the distinct key
      int idx = atomicAdd(Kp, 1);
      pairs[idx] = ((unsigned int)rnk[a] << 16) | (unsigned int)rnk[b];
      return;
    }
    if (old == key) return;                // duplicate
    ++h;
  }
}

// ---------- 7a. pack sign bits: packed[word][node]; node-major threads -> coalesced writes ----------
__global__ __launch_bounds__(256) void pack_kernel(const float* __restrict__ W,
                                                   unsigned int* __restrict__ packed) {
  int t = blockIdx.x * 256 + threadIdx.x;
  if (t >= NN * WORDS) return;
  int w = t / NN;
  int node = t - w * NN;               // consecutive threads -> consecutive nodes, same word
  int d0 = w * 32;
  const float* p = W + (size_t)node * DIM + d0;   // 128B-aligned per-lane chunk
  unsigned int m = 0;
  if (d0 + 32 <= DIM) {
#pragma unroll
    for (int q = 0; q < 8; ++q) {
      float4 v4 = *reinterpret_cast<const float4*>(p + q * 4);
      m |= (__float_as_uint(v4.x) >> 31) << (q * 4);
      m |= (__float_as_uint(v4.y) >> 31) << (q * 4 + 1);
      m |= (__float_as_uint(v4.z) >> 31) << (q * 4 + 2);
      m |= (__float_as_uint(v4.w) >> 31) << (q * 4 + 3);
    }
  } else {
    for (int j = 0; j < DIM - d0; ++j) m |= (__float_as_uint(p[j]) >> 31) << j;
  }
  packed[(size_t)w * NN + node] = m;   // coalesced
}

// ---------- 7b. per-dim xor-bit counts via ballot+popcount, edge-split grid ----------
__global__ __launch_bounds__(256) void encpop_kernel(char* __restrict__ ws) {
  const unsigned int* packed = (const unsigned int*)(ws + WS_PACK);
  const unsigned int* pairs = (const unsigned int*)(ws + WS_PAIRS);
  const int* Kp = (const int*)(ws + WS_K);
  int* enc_int = (int*)(ws + WS_ENC);
  __shared__ unsigned int s_col[NN];   // this word's bits for all 2000 rows (by rank)
  __shared__ int s_part[4][32];
  int w = blockIdx.x;
  int tid = threadIdx.x;
  int wid = tid >> 6, lane = tid & 63;
  for (int i = tid; i < NN; i += 256) s_col[i] = packed[(size_t)w * NN + i];
  __syncthreads();
  int K = *Kp;
  const int per = NE / ECH;            // 1024
  int e0 = blockIdx.y * per;
  int cnt[32];
#pragma unroll
  for (int b = 0; b < 32; ++b) cnt[b] = 0;
  for (int e = e0 + tid; e < e0 + per; e += 256) {   // uniform trip count: ballot-safe
    unsigned int x = 0;
    if (e < K) {
      unsigned int pk = pairs[e];
      x = s_col[pk >> 16] ^ s_col[pk & 0xffffu];
    }
#pragma unroll
    for (int b = 0; b < 32; ++b)
      cnt[b] += (int)__popcll(__ballot(x & (1u << b)));   // uniform per wave
  }
  if (lane == 0) {
#pragma unroll
    for (int b = 0; b < 32; ++b) s_part[wid][b] = cnt[b];
  }
  __syncthreads();
  if (tid < 32) {
    int tot = s_part[0][tid] + s_part[1][tid] + s_part[2][tid] + s_part[3][tid];
    if (tot) atomicAdd(&enc_int[w * 32 + tid], tot);   // exact integer accumulation
  }
}

// ---------- 8. out[c] = sum_d (K - 2*cnt[d]) * Wc[c][d] ----------
__global__ __launch_bounds__(256) void out_kernel(const float* __restrict__ Wc,
                                                  char* __restrict__ ws,
                                                  float* __restrict__ out) {
  const int* enc_int = (const int*)(ws + WS_ENC);
  int K = *(const int*)(ws + WS_K);
  __shared__ float red[4];
  int c = blockIdx.x;
  float s = 0.f;
  for (int d = threadIdx.x; d < DIM; d += 256)
    s += (float)(K - 2 * enc_int[d]) * Wc[c * DIM + d];
  for (int o = 32; o > 0; o >>= 1) s += __shfl_down(s, o, 64);
  if ((threadIdx.x & 63) == 0) red[threadIdx.x >> 6] = s;
  __syncthreads();
  if (threadIdx.x == 0) out[c] = red[0] + red[1] + red[2] + red[3];
}

extern "C" void kernel_launch(void* const* d_in, const int* in_sizes, int n_in,
                              void* d_out, int out_size, void* d_ws, size_t ws_size,
                              hipStream_t stream) {
  const int* eidx = (const int*)d_in[0];        // edge_index int32 [2, 8192]
  const float* Wn = (const float*)d_in[1];      // node_ids_weight f32 [2000, 10000]
  const float* Wc = (const float*)d_in[2];      // classify_weight f32 [10, 10000]
  float* out = (float*)d_out;
  char* ws = (char*)d_ws;

  init_kernel<<<(INIT_TOT + 255) / 256, 256, 0, stream>>>(ws);

  // pack is independent of the graph pipeline; issue it early
  pack_kernel<<<(NN * WORDS + 255) / 256, 256, 0, stream>>>(Wn, (unsigned int*)(ws + WS_PACK));

  count_kernel<<<NCHUNK, CPE, 0, stream>>>(eidx, (int*)(ws + WS_DEG), (int*)(ws + WS_CHUNK));
  scan_kernel<<<1, 1024, 0, stream>>>((int*)(ws + WS_BASE), (int*)(ws + WS_CHUNK));
  fill_kernel<<<NCHUNK, CPE, 0, stream>>>(eidx, (const int*)(ws + WS_CHUNK),
                                          (unsigned short*)(ws + WS_CCOL));
  pr_kernel<<<1, 1024, 0, stream>>>(ws);
  rank_kernel<<<(NN + RBLK - 1) / RBLK, 256, 0, stream>>>(ws);
  dedup_kernel<<<NE / 256, 256, 0, stream>>>(eidx, ws);
  encpop_kernel<<<dim3(WORDS, ECH), 256, 0, stream>>>(ws);
  out_kernel<<<NCLS, 256, 0, stream>>>(Wc, ws, out);
}